// Round 13
// baseline (83.705 us; speedup 1.0000x reference)
//
#include <hip/hip_runtime.h>
#include <stdint.h>

#define BATCH 256
#define DBLK  16          // d
#define OB    128         // hidden nodes per diagonal block (M)
#define NN    2048        // M*D

using bf16x8  = __attribute__((ext_vector_type(8))) __bf16;
using f32x4   = __attribute__((ext_vector_type(4))) float;
using ushort8 = __attribute__((ext_vector_type(8))) unsigned short;

__device__ __forceinline__ unsigned short f2bf(float f) {
    union { float f; uint32_t u; } v; v.f = f;
    uint32_t u = v.u;
    uint32_t r = (u + 0x7fffu + ((u >> 16) & 1u)) >> 16;   // RNE
    return (unsigned short)r;
}

__device__ __forceinline__ float bf2f(unsigned short h) {
    union { uint32_t u; float f; } v; v.u = ((uint32_t)h) << 16;
    return v.f;
}

// fp32x8 -> bf16x8 in-register (compiler emits v_cvt_pk_bf16_f32 pairs)
__device__ __forceinline__ bf16x8 cvt_bf8(float4 a, float4 b) {
    bf16x8 r;
    r[0] = (__bf16)a.x; r[1] = (__bf16)a.y; r[2] = (__bf16)a.z; r[3] = (__bf16)a.w;
    r[4] = (__bf16)b.x; r[5] = (__bf16)b.y; r[6] = (__bf16)b.z; r[7] = (__bf16)b.w;
    return r;
}

// fused fast tanh + log|tanh'|: one __expf + one __logf.
__device__ __forceinline__ void act_tanh_lga(float x, float& th, float& lga) {
    float ax = fabsf(x);
    float e  = __expf(-2.f * ax);
    float p  = 1.f + e;
    float t  = 1.f - __fdividef(2.f * e, p);
    th  = (x < 0.f) ? -t : t;
    lga = 2.f * (0.69314718055994531f - ax - __logf(p));
}

// ---- layer0, 512 threads: thread t -> outputs j = (t>>5)*128 + (t&31)*4 ..+3
__device__ __forceinline__ void l0_block512(const float* __restrict__ xs,
                                            const float* __restrict__ W0,
                                            const float* __restrict__ b0,
                                            unsigned short* __restrict__ h0,
                                            unsigned short* __restrict__ e0,
                                            float* __restrict__ mmax,
                                            int b, int t) {
    const int dd = t >> 5;
    const int j0 = dd * OB + (t & 31) * 4;
    float g[4];
    unsigned short hv[4];
    float lm = -1e30f;
    #pragma unroll
    for (int q = 0; q < 4; ++q) {
        const int j = j0 + q;
        const float* wrow = W0 + (size_t)j * DBLK;
        float s = b0[j];
        #pragma unroll
        for (int c = 0; c < DBLK; c += 4) {
            float4 wv = *(const float4*)(wrow + c);
            s += wv.x * xs[c] + wv.y * xs[c + 1] + wv.z * xs[c + 2] + wv.w * xs[c + 3];
        }
        float th, lga;
        act_tanh_lga(s, th, lga);
        hv[q] = f2bf(th);
        g[q]  = __logf(wrow[dd]) + lga;
        lm = fmaxf(lm, g[q]);
    }
    #pragma unroll
    for (int off = 1; off < 32; off <<= 1) lm = fmaxf(lm, __shfl_xor(lm, off));
    ushort4 hh, ee;
    #pragma unroll
    for (int q = 0; q < 4; ++q) {
        ((unsigned short*)&hh)[q] = hv[q];
        ((unsigned short*)&ee)[q] = f2bf(__expf(g[q] - lm));
    }
    *(ushort4*)(h0 + (size_t)b * NN + j0) = hh;
    *(ushort4*)(e0 + (size_t)b * NN + j0) = ee;
    if ((t & 31) == 0) mmax[b * DBLK + dd] = lm;
}

// ---- P1: layer0 of flow 0 only (one batch row per block)
__global__ void __launch_bounds__(512)
k_l0(const float* __restrict__ inp,
     const float* __restrict__ W00,
     const float* __restrict__ b00,
     unsigned short* __restrict__ h0,
     unsigned short* __restrict__ e0,
     float* __restrict__ mmax) {
    l0_block512(inp + (size_t)blockIdx.x * DBLK, W00, b00, h0, e0, mmax,
                blockIdx.x, threadIdx.x);
}

// ---- layer1. 512 thr (8 waves). Output tile = 32 rows x 32 cols (2 bt halves
// share B loads). B = W1 read DIRECTLY as fp32, converted in-register (the
// GEMM is latency-bound with idle VALU — conversion is free; eliminates the
// separate convert pipeline). Waves split K 8 ways interleaved.
// grid (16,8,4): dd = 15-x (heavy dd dispatched first).
__global__ void __launch_bounds__(512, 2)
k_l1(const unsigned short* __restrict__ h0,
     const float* __restrict__ W1f,       // fp32, block-lower-triangular
     const float* __restrict__ b1v,
     const unsigned short* __restrict__ e0,
     const float* __restrict__ mmax,
     unsigned short* __restrict__ h1,
     float* __restrict__ g1) {
    const int tid = threadIdx.x;
    const int dd  = 15 - (int)blockIdx.x;
    const int btp   = blockIdx.y;    // 0..7  (pair of 16-row tiles)
    const int ct    = blockIdx.z;    // 0..3
    const int w     = tid >> 6;      // 0..7
    const int lane  = tid & 63;
    const int brow0 = btp * 32;
    const int arow0 = brow0 + (lane & 15);
    const int arow1 = arow0 + 16;
    const int koff  = (lane >> 4) * 8;
    const int ncol  = lane & 15;
    const int col0  = dd * OB + ct * 32;

    f32x4 acc[2][2], acc2[2][2];
    #pragma unroll
    for (int hh = 0; hh < 2; ++hh)
        #pragma unroll
        for (int nt = 0; nt < 2; ++nt) {
            acc[hh][nt]  = (f32x4){0.f, 0.f, 0.f, 0.f};
            acc2[hh][nt] = (f32x4){0.f, 0.f, 0.f, 0.f};
        }

    const unsigned short* Ab0 = h0 + (size_t)arow0 * NN + koff;
    const unsigned short* Ab1 = h0 + (size_t)arow1 * NN + koff;
    const float* Bf[2];
    #pragma unroll
    for (int nt = 0; nt < 2; ++nt)
        Bf[nt] = W1f + (size_t)(col0 + nt * 16 + ncol) * NN + koff;

    // grad-matvec loads hoisted before the GEMM chain (waves 0..3 use them)
    bf16x8 ga0 = {}, ga1 = {}, gb0 = {}, gb1 = {};
    if (w < 4) {
        const int k2 = dd * OB + w * 32;
        ga0 = *(const bf16x8*)(e0 + (size_t)arow0 * NN + koff + k2);
        ga1 = *(const bf16x8*)(e0 + (size_t)arow1 * NN + koff + k2);
        float4 g00 = *(const float4*)(Bf[0] + k2);
        float4 g01 = *(const float4*)(Bf[0] + k2 + 4);
        float4 g10 = *(const float4*)(Bf[1] + k2);
        float4 g11 = *(const float4*)(Bf[1] + k2 + 4);
        gb0 = cvt_bf8(g00, g01);
        gb1 = cvt_bf8(g10, g11);
    }

    // GEMM: wave w takes chunks c = w, w+8, ... of the (dd+1)*4 chunks
    const int nch = (dd + 1) * 4;
    #pragma unroll 2
    for (int c = w; c < nch; c += 8) {
        const int k = c * 32;
        bf16x8 a0  = *(const bf16x8*)(Ab0 + k);
        bf16x8 a1  = *(const bf16x8*)(Ab1 + k);
        float4 c00 = *(const float4*)(Bf[0] + k);
        float4 c01 = *(const float4*)(Bf[0] + k + 4);
        float4 c10 = *(const float4*)(Bf[1] + k);
        float4 c11 = *(const float4*)(Bf[1] + k + 4);
        bf16x8 b0v = cvt_bf8(c00, c01);
        bf16x8 b1w = cvt_bf8(c10, c11);
        acc[0][0] = __builtin_amdgcn_mfma_f32_16x16x32_bf16(a0, b0v, acc[0][0], 0, 0, 0);
        acc[0][1] = __builtin_amdgcn_mfma_f32_16x16x32_bf16(a0, b1w, acc[0][1], 0, 0, 0);
        acc[1][0] = __builtin_amdgcn_mfma_f32_16x16x32_bf16(a1, b0v, acc[1][0], 0, 0, 0);
        acc[1][1] = __builtin_amdgcn_mfma_f32_16x16x32_bf16(a1, b1w, acc[1][1], 0, 0, 0);
    }

    if (w < 4) {
        acc2[0][0] = __builtin_amdgcn_mfma_f32_16x16x32_bf16(ga0, gb0, acc2[0][0], 0, 0, 0);
        acc2[0][1] = __builtin_amdgcn_mfma_f32_16x16x32_bf16(ga0, gb1, acc2[0][1], 0, 0, 0);
        acc2[1][0] = __builtin_amdgcn_mfma_f32_16x16x32_bf16(ga1, gb0, acc2[1][0], 0, 0, 0);
        acc2[1][1] = __builtin_amdgcn_mfma_f32_16x16x32_bf16(ga1, gb1, acc2[1][1], 0, 0, 0);
    }

    __shared__ float ls1[8][2][2][64][4];   // [w][half][nt][lane][r]  32 KB
    __shared__ float ls2[4][2][2][64][4];   //                         16 KB
    #pragma unroll
    for (int hh = 0; hh < 2; ++hh)
        #pragma unroll
        for (int nt = 0; nt < 2; ++nt)
            *(f32x4*)&ls1[w][hh][nt][lane][0] = acc[hh][nt];
    if (w < 4) {
        #pragma unroll
        for (int hh = 0; hh < 2; ++hh)
            #pragma unroll
            for (int nt = 0; nt < 2; ++nt)
                *(f32x4*)&ls2[w][hh][nt][lane][0] = acc2[hh][nt];
    }
    __syncthreads();

    #pragma unroll
    for (int half = 0; half < 2; ++half) {
        const int o   = tid;                   // 512 outputs per half
        const int rr2 = o >> 5;                // 0..15 row within half
        const int cc  = o & 31;                // 0..31 col in tile
        const int nt  = cc >> 4;
        const int r   = rr2 & 3;
        const int ls  = (rr2 >> 2) * 16 + (cc & 15);
        float S = 0.f, S2 = 0.f;
        #pragma unroll
        for (int ww = 0; ww < 8; ++ww) S += ls1[ww][half][nt][ls][r];
        #pragma unroll
        for (int ww = 0; ww < 4; ++ww) S2 += ls2[ww][half][nt][ls][r];
        const int j    = col0 + cc;
        const int brow = brow0 + half * 16 + rr2;
        const float pre = S + b1v[j];
        float th, lga;
        act_tanh_lga(pre, th, lga);
        h1[(size_t)brow * NN + j] = f2bf(th);
        g1[(size_t)brow * NN + j] = __logf(S2) + mmax[brow * DBLK + dd] + lga;
    }
}

// ---- final-layer compute for one batch row, 512 threads: wave w -> dd = w, w+8.
__device__ __forceinline__ float final_compute(const unsigned short* __restrict__ h1,
                                               const float* __restrict__ g1,
                                               const float* __restrict__ W2,
                                               int b, int t,
                                               float* sh, float* gf, float* sx) {
    const int wave = t >> 6;
    const int lane = t & 63;
    {
        const int k = t * 4;
        ushort4 hv = *(const ushort4*)(h1 + (size_t)b * NN + k);
        float4 f0;
        f0.x = bf2f(hv.x); f0.y = bf2f(hv.y); f0.z = bf2f(hv.z); f0.w = bf2f(hv.w);
        *(float4*)(sh + k) = f0;
    }
    __syncthreads();

    #pragma unroll
    for (int q = 0; q < 2; ++q) {
        const int dd = wave + q * 8;           // balanced: (w+1)+(w+9) const
        const float* w2r = W2 + (size_t)dd * NN;
        const int kend = (dd + 1) * OB;
        float s = 0.f;
        for (int k = lane * 4; k < kend; k += 64 * 4) {
            float4 hv = *(const float4*)(sh + k);
            float4 wv = *(const float4*)(w2r + k);
            s += hv.x * wv.x + hv.y * wv.y + hv.z * wv.z + hv.w * wv.w;
        }
        #pragma unroll
        for (int off = 32; off > 0; off >>= 1) s += __shfl_xor(s, off);
        float v0 = g1[(size_t)b * NN + dd * OB + lane];
        float v1 = g1[(size_t)b * NN + dd * OB + 64 + lane];
        float m = fmaxf(v0, v1);
        #pragma unroll
        for (int off = 32; off > 0; off >>= 1) m = fmaxf(m, __shfl_xor(m, off));
        float e = __expf(v0 - m) * w2r[dd * OB + lane]
                + __expf(v1 - m) * w2r[dd * OB + 64 + lane];
        #pragma unroll
        for (int off = 32; off > 0; off >>= 1) e += __shfl_xor(e, off);
        if (lane == 0) {
            sx[dd] = s;
            gf[dd] = __logf(e) + m;
        }
    }
    __syncthreads();
    float ld = 0.f;
    #pragma unroll
    for (int dd = 0; dd < DBLK; ++dd) ld += gf[dd];
    return ld;
}

// ---- P3: final of flow 0 + layer0 of flow 1 (block b = batch row b)
__global__ void __launch_bounds__(512)
k_fin0(const unsigned short* __restrict__ h1,
       const float* __restrict__ g1,
       const float* __restrict__ W2,   // flow 0
       const float* __restrict__ W0n,  // flow 1
       const float* __restrict__ b0n,  // flow 1
       unsigned short* __restrict__ h0,
       unsigned short* __restrict__ e0,
       float* __restrict__ mmax,
       float* __restrict__ ld0) {
    __shared__ float sh[NN];
    __shared__ float gf[DBLK];
    __shared__ float sx[DBLK];
    const int b = blockIdx.x;
    const int t = threadIdx.x;
    float ld = final_compute(h1, g1, W2, b, t, sh, gf, sx);
    if (t == 0) ld0[b] = ld;
    l0_block512(sx, W0n, b0n, h0, e0, mmax, b, t);
}

// ---- P5: final of flow 1 -> d_out
__global__ void __launch_bounds__(512)
k_fin1(const unsigned short* __restrict__ h1,
       const float* __restrict__ g1,
       const float* __restrict__ W2,   // flow 1
       const float* __restrict__ ld0,
       float* __restrict__ out_final,
       float* __restrict__ ld_final) {
    __shared__ float sh[NN];
    __shared__ float gf[DBLK];
    __shared__ float sx[DBLK];
    const int b = blockIdx.x;
    const int t = threadIdx.x;
    float ld = final_compute(h1, g1, W2, b, t, sh, gf, sx);
    if (t < DBLK) out_final[b * DBLK + t] = sx[t];
    if (t == 0) ld_final[b] = ld + ld0[b];
}

extern "C" void kernel_launch(void* const* d_in, const int* in_sizes, int n_in,
                              void* d_out, int out_size, void* d_ws, size_t ws_size,
                              hipStream_t stream) {
    const float* inp   = (const float*)d_in[0];
    const float* W0[2] = {(const float*)d_in[1], (const float*)d_in[6]};
    const float* W1[2] = {(const float*)d_in[2], (const float*)d_in[7]};
    const float* W2[2] = {(const float*)d_in[3], (const float*)d_in[8]};
    const float* b0[2] = {(const float*)d_in[4], (const float*)d_in[9]};
    const float* b1[2] = {(const float*)d_in[5], (const float*)d_in[10]};

    char* w = (char*)d_ws;
    size_t off = 0;
    unsigned short* h0b  = (unsigned short*)(w + off); off += (size_t)BATCH * NN * 2;
    unsigned short* e0b  = (unsigned short*)(w + off); off += (size_t)BATCH * NN * 2;
    float* mmax = (float*)(w + off); off += (size_t)BATCH * DBLK * 4;
    unsigned short* h1 = (unsigned short*)(w + off); off += (size_t)BATCH * NN * 2;
    float* g1   = (float*)(w + off); off += (size_t)BATCH * NN * 4;
    float* ld0  = (float*)(w + off); off += (size_t)BATCH * 4;

    float* out_final = (float*)d_out;                 // (256,16)
    float* ld_final  = (float*)d_out + BATCH * DBLK;  // (256,)

    // P1: layer0 flow 0 (no conversion stage — W1 is consumed fp32 in-GEMM)
    k_l0<<<dim3(BATCH), dim3(512), 0, stream>>>(
        inp, W0[0], b0[0], h0b, e0b, mmax);

    // P2: layer1 flow 0 (fp32 W1, in-register convert; dd descending)
    k_l1<<<dim3(16, 8, 4), dim3(512), 0, stream>>>(
        h0b, W1[0], b1[0], e0b, mmax, h1, g1);

    // P3: final flow 0 + layer0 flow 1
    k_fin0<<<dim3(BATCH), dim3(512), 0, stream>>>(
        h1, g1, W2[0], W0[1], b0[1], h0b, e0b, mmax, ld0);

    // P4: layer1 flow 1
    k_l1<<<dim3(16, 8, 4), dim3(512), 0, stream>>>(
        h0b, W1[1], b1[1], e0b, mmax, h1, g1);

    // P5: final flow 1
    k_fin1<<<dim3(BATCH), dim3(512), 0, stream>>>(
        h1, g1, W2[1], ld0, out_final, ld_final);
}

// Round 14
// 76.473 us; speedup vs baseline: 1.0946x; 1.0946x over previous
//
#include <hip/hip_runtime.h>
#include <stdint.h>

#define BATCH 256
#define DBLK  16          // d
#define OB    128         // hidden nodes per diagonal block (M)
#define NN    2048        // M*D

using bf16x8  = __attribute__((ext_vector_type(8))) __bf16;
using f32x4   = __attribute__((ext_vector_type(4))) float;
using ushort8 = __attribute__((ext_vector_type(8))) unsigned short;

__device__ __forceinline__ unsigned short f2bf(float f) {
    union { float f; uint32_t u; } v; v.f = f;
    uint32_t u = v.u;
    uint32_t r = (u + 0x7fffu + ((u >> 16) & 1u)) >> 16;   // RNE
    return (unsigned short)r;
}

__device__ __forceinline__ float bf2f(unsigned short h) {
    union { uint32_t u; float f; } v; v.u = ((uint32_t)h) << 16;
    return v.f;
}

// fused fast tanh + log|tanh'|: one __expf + one __logf.
__device__ __forceinline__ void act_tanh_lga(float x, float& th, float& lga) {
    float ax = fabsf(x);
    float e  = __expf(-2.f * ax);
    float p  = 1.f + e;
    float t  = 1.f - __fdividef(2.f * e, p);
    th  = (x < 0.f) ? -t : t;
    lga = 2.f * (0.69314718055994531f - ax - __logf(p));
}

__device__ __forceinline__ ushort8 pack_bf8(float4 a, float4 b) {
    ushort8 u;
    u[0] = f2bf(a.x); u[1] = f2bf(a.y); u[2] = f2bf(a.z); u[3] = f2bf(a.w);
    u[4] = f2bf(b.x); u[5] = f2bf(b.y); u[6] = f2bf(b.z); u[7] = f2bf(b.w);
    return u;
}

// ---- convert 8 row-pairs {p,2047-p} of one W1 (fp32->bf16, triangular extent).
// 512 threads, 2176 8-float chunks, 5 hoisted load slots per thread.
__device__ __forceinline__ void conv8pairs(int cid, int tid,
                                           const float* __restrict__ Wsrc,
                                           unsigned short* __restrict__ Wdst) {
    float4 va[5][2];
    unsigned short* dp[5];
    bool act[5];
    #pragma unroll
    for (int i = 0; i < 5; ++i) {
        const int c = tid + i * 512;
        act[i] = (c < 2176);
        if (act[i]) {
            const int pi  = c / 272;
            const int rem = c - pi * 272;
            const int p   = cid * 8 + pi;
            const int kend0 = ((p >> 7) + 1) * OB;
            const int off = rem * 8;
            const int row = (off < kend0) ? p : (NN - 1 - p);
            const int k   = (off < kend0) ? off : (off - kend0);
            const float* sp = Wsrc + (size_t)row * NN + k;
            dp[i] = Wdst + (size_t)row * NN + k;
            va[i][0] = *(const float4*)(sp);
            va[i][1] = *(const float4*)(sp + 4);
        }
    }
    #pragma unroll
    for (int i = 0; i < 5; ++i)
        if (act[i]) *(ushort8*)dp[i] = pack_bf8(va[i][0], va[i][1]);
}

// ---- layer0, 512 threads: thread t -> outputs j = (t>>5)*128 + (t&31)*4 ..+3
__device__ __forceinline__ void l0_block512(const float* __restrict__ xs,
                                            const float* __restrict__ W0,
                                            const float* __restrict__ b0,
                                            unsigned short* __restrict__ h0,
                                            unsigned short* __restrict__ e0,
                                            float* __restrict__ mmax,
                                            int b, int t) {
    const int dd = t >> 5;
    const int j0 = dd * OB + (t & 31) * 4;
    float g[4];
    unsigned short hv[4];
    float lm = -1e30f;
    #pragma unroll
    for (int q = 0; q < 4; ++q) {
        const int j = j0 + q;
        const float* wrow = W0 + (size_t)j * DBLK;
        float s = b0[j];
        #pragma unroll
        for (int c = 0; c < DBLK; c += 4) {
            float4 wv = *(const float4*)(wrow + c);
            s += wv.x * xs[c] + wv.y * xs[c + 1] + wv.z * xs[c + 2] + wv.w * xs[c + 3];
        }
        float th, lga;
        act_tanh_lga(s, th, lga);
        hv[q] = f2bf(th);
        g[q]  = __logf(wrow[dd]) + lga;
        lm = fmaxf(lm, g[q]);
    }
    #pragma unroll
    for (int off = 1; off < 32; off <<= 1) lm = fmaxf(lm, __shfl_xor(lm, off));
    ushort4 hh, ee;
    #pragma unroll
    for (int q = 0; q < 4; ++q) {
        ((unsigned short*)&hh)[q] = hv[q];
        ((unsigned short*)&ee)[q] = f2bf(__expf(g[q] - lm));
    }
    *(ushort4*)(h0 + (size_t)b * NN + j0) = hh;
    *(ushort4*)(e0 + (size_t)b * NN + j0) = ee;
    if ((t & 31) == 0) mmax[b * DBLK + dd] = lm;
}

// ---- P1: blocks [0,128): convert flow0 W1 (8 row-pairs each, deep pipeline);
//          blocks [128,384): layer0 of flow 0
__global__ void __launch_bounds__(512)
k_prep(const float* __restrict__ W1a,
       unsigned short* __restrict__ W1bf,
       const float* __restrict__ inp,
       const float* __restrict__ W00,
       const float* __restrict__ b00,
       unsigned short* __restrict__ h0,
       unsigned short* __restrict__ e0,
       float* __restrict__ mmax) {
    const int gb = blockIdx.x;
    const int t  = threadIdx.x;
    if (gb < 128) {
        conv8pairs(gb, t, W1a, W1bf);
    } else {
        const int b = gb - 128;
        l0_block512(inp + (size_t)b * DBLK, W00, b00, h0, e0, mmax, b, t);
    }
}

// ---- layer1. 512 thr (8 waves). Output tile = 32 rows x 32 cols (2 bt halves
// share B loads: 4 loads -> 4 MFMA per chunk). Waves split K 8 ways interleaved.
// CONV grid (20,8,4): x<4 = convert flow1 W1, x>=4 = GEMM with dd = 19-x.
// !CONV grid (16,8,4): dd = 15-x (heavy dd dispatched first).
template<bool CONV>
__global__ void __launch_bounds__(512, 2)
k_l1(const unsigned short* __restrict__ h0,
     const unsigned short* __restrict__ W1b,
     const float* __restrict__ b1v,
     const unsigned short* __restrict__ e0,
     const float* __restrict__ mmax,
     unsigned short* __restrict__ h1,
     float* __restrict__ g1,
     const float* __restrict__ W1next,
     unsigned short* __restrict__ W1bfn) {
    const int tid = threadIdx.x;

    int dd;
    if (CONV) {
        if (blockIdx.x < 4) {
            const int cid = (int)blockIdx.x * 32 + (int)blockIdx.y * 4 + (int)blockIdx.z;
            conv8pairs(cid, tid, W1next, W1bfn);
            return;
        }
        dd = 19 - (int)blockIdx.x;
    } else {
        dd = 15 - (int)blockIdx.x;
    }
    const int btp   = blockIdx.y;    // 0..7  (pair of 16-row tiles)
    const int ct    = blockIdx.z;    // 0..3
    const int w     = tid >> 6;      // 0..7
    const int lane  = tid & 63;
    const int brow0 = btp * 32;
    const int arow0 = brow0 + (lane & 15);
    const int arow1 = arow0 + 16;
    const int koff  = (lane >> 4) * 8;
    const int ncol  = lane & 15;
    const int col0  = dd * OB + ct * 32;

    f32x4 acc[2][2], acc2[2][2];
    #pragma unroll
    for (int hh = 0; hh < 2; ++hh)
        #pragma unroll
        for (int nt = 0; nt < 2; ++nt) {
            acc[hh][nt]  = (f32x4){0.f, 0.f, 0.f, 0.f};
            acc2[hh][nt] = (f32x4){0.f, 0.f, 0.f, 0.f};
        }

    const unsigned short* Ab0 = h0 + (size_t)arow0 * NN + koff;
    const unsigned short* Ab1 = h0 + (size_t)arow1 * NN + koff;
    const unsigned short* Bb[2];
    #pragma unroll
    for (int nt = 0; nt < 2; ++nt)
        Bb[nt] = W1b + (size_t)(col0 + nt * 16 + ncol) * NN + koff;

    // grad-matvec loads hoisted before the GEMM chain (waves 0..3 use them)
    bf16x8 ga0 = {}, ga1 = {}, gb0 = {}, gb1 = {};
    if (w < 4) {
        const int k2 = dd * OB + w * 32;
        ga0 = *(const bf16x8*)(e0 + (size_t)arow0 * NN + koff + k2);
        ga1 = *(const bf16x8*)(e0 + (size_t)arow1 * NN + koff + k2);
        gb0 = *(const bf16x8*)(Bb[0] + k2);
        gb1 = *(const bf16x8*)(Bb[1] + k2);
    }

    // epilogue operand prefetch: these are needed after the LDS combine —
    // issue now so their latency hides under the K-loop + barrier.
    const int ep_rr  = tid >> 5;            // 0..15 row within half
    const int ep_cc  = tid & 31;            // 0..31 col in tile
    const int ep_j   = col0 + ep_cc;
    const float ep_bias = b1v[ep_j];
    const float ep_m0 = mmax[(brow0 + ep_rr) * DBLK + dd];
    const float ep_m1 = mmax[(brow0 + 16 + ep_rr) * DBLK + dd];

    // GEMM: wave w takes chunks c = w, w+8, ... of the (dd+1)*4 chunks
    const int nch = (dd + 1) * 4;
    #pragma unroll 4
    for (int c = w; c < nch; c += 8) {
        const int k = c * 32;
        bf16x8 a0  = *(const bf16x8*)(Ab0 + k);
        bf16x8 a1  = *(const bf16x8*)(Ab1 + k);
        bf16x8 b0v = *(const bf16x8*)(Bb[0] + k);
        bf16x8 b1w = *(const bf16x8*)(Bb[1] + k);
        acc[0][0] = __builtin_amdgcn_mfma_f32_16x16x32_bf16(a0, b0v, acc[0][0], 0, 0, 0);
        acc[0][1] = __builtin_amdgcn_mfma_f32_16x16x32_bf16(a0, b1w, acc[0][1], 0, 0, 0);
        acc[1][0] = __builtin_amdgcn_mfma_f32_16x16x32_bf16(a1, b0v, acc[1][0], 0, 0, 0);
        acc[1][1] = __builtin_amdgcn_mfma_f32_16x16x32_bf16(a1, b1w, acc[1][1], 0, 0, 0);
    }

    if (w < 4) {
        acc2[0][0] = __builtin_amdgcn_mfma_f32_16x16x32_bf16(ga0, gb0, acc2[0][0], 0, 0, 0);
        acc2[0][1] = __builtin_amdgcn_mfma_f32_16x16x32_bf16(ga0, gb1, acc2[0][1], 0, 0, 0);
        acc2[1][0] = __builtin_amdgcn_mfma_f32_16x16x32_bf16(ga1, gb0, acc2[1][0], 0, 0, 0);
        acc2[1][1] = __builtin_amdgcn_mfma_f32_16x16x32_bf16(ga1, gb1, acc2[1][1], 0, 0, 0);
    }

    __shared__ float ls1[8][2][2][64][4];   // [w][half][nt][lane][r]  32 KB
    __shared__ float ls2[4][2][2][64][4];   //                         16 KB
    #pragma unroll
    for (int hh = 0; hh < 2; ++hh)
        #pragma unroll
        for (int nt = 0; nt < 2; ++nt)
            *(f32x4*)&ls1[w][hh][nt][lane][0] = acc[hh][nt];
    if (w < 4) {
        #pragma unroll
        for (int hh = 0; hh < 2; ++hh)
            #pragma unroll
            for (int nt = 0; nt < 2; ++nt)
                *(f32x4*)&ls2[w][hh][nt][lane][0] = acc2[hh][nt];
    }
    __syncthreads();

    #pragma unroll
    for (int half = 0; half < 2; ++half) {
        const int nt  = ep_cc >> 4;
        const int r   = ep_rr & 3;
        const int ls  = (ep_rr >> 2) * 16 + (ep_cc & 15);
        float S = 0.f, S2 = 0.f;
        #pragma unroll
        for (int ww = 0; ww < 8; ++ww) S += ls1[ww][half][nt][ls][r];
        #pragma unroll
        for (int ww = 0; ww < 4; ++ww) S2 += ls2[ww][half][nt][ls][r];
        const int brow = brow0 + half * 16 + ep_rr;
        const float pre = S + ep_bias;
        float th, lga;
        act_tanh_lga(pre, th, lga);
        h1[(size_t)brow * NN + ep_j] = f2bf(th);
        g1[(size_t)brow * NN + ep_j] = __logf(S2) + (half ? ep_m1 : ep_m0) + lga;
    }
}

// ---- final-layer compute for one batch row, 512 threads: wave w -> dd = w, w+8.
__device__ __forceinline__ float final_compute(const unsigned short* __restrict__ h1,
                                               const float* __restrict__ g1,
                                               const float* __restrict__ W2,
                                               int b, int t,
                                               float* sh, float* gf, float* sx) {
    const int wave = t >> 6;
    const int lane = t & 63;
    {
        const int k = t * 4;
        ushort4 hv = *(const ushort4*)(h1 + (size_t)b * NN + k);
        float4 f0;
        f0.x = bf2f(hv.x); f0.y = bf2f(hv.y); f0.z = bf2f(hv.z); f0.w = bf2f(hv.w);
        *(float4*)(sh + k) = f0;
    }
    __syncthreads();

    #pragma unroll
    for (int q = 0; q < 2; ++q) {
        const int dd = wave + q * 8;           // balanced: (w+1)+(w+9) const
        const float* w2r = W2 + (size_t)dd * NN;
        const int kend = (dd + 1) * OB;
        float s = 0.f;
        for (int k = lane * 4; k < kend; k += 64 * 4) {
            float4 hv = *(const float4*)(sh + k);
            float4 wv = *(const float4*)(w2r + k);
            s += hv.x * wv.x + hv.y * wv.y + hv.z * wv.z + hv.w * wv.w;
        }
        #pragma unroll
        for (int off = 32; off > 0; off >>= 1) s += __shfl_xor(s, off);
        float v0 = g1[(size_t)b * NN + dd * OB + lane];
        float v1 = g1[(size_t)b * NN + dd * OB + 64 + lane];
        float m = fmaxf(v0, v1);
        #pragma unroll
        for (int off = 32; off > 0; off >>= 1) m = fmaxf(m, __shfl_xor(m, off));
        float e = __expf(v0 - m) * w2r[dd * OB + lane]
                + __expf(v1 - m) * w2r[dd * OB + 64 + lane];
        #pragma unroll
        for (int off = 32; off > 0; off >>= 1) e += __shfl_xor(e, off);
        if (lane == 0) {
            sx[dd] = s;
            gf[dd] = __logf(e) + m;
        }
    }
    __syncthreads();
    float ld = 0.f;
    #pragma unroll
    for (int dd = 0; dd < DBLK; ++dd) ld += gf[dd];
    return ld;
}

// ---- P3: final of flow 0 + layer0 of flow 1 (block b = batch row b)
__global__ void __launch_bounds__(512)
k_fin0(const unsigned short* __restrict__ h1,
       const float* __restrict__ g1,
       const float* __restrict__ W2,   // flow 0
       const float* __restrict__ W0n,  // flow 1
       const float* __restrict__ b0n,  // flow 1
       unsigned short* __restrict__ h0,
       unsigned short* __restrict__ e0,
       float* __restrict__ mmax,
       float* __restrict__ ld0) {
    __shared__ float sh[NN];
    __shared__ float gf[DBLK];
    __shared__ float sx[DBLK];
    const int b = blockIdx.x;
    const int t = threadIdx.x;
    float ld = final_compute(h1, g1, W2, b, t, sh, gf, sx);
    if (t == 0) ld0[b] = ld;
    l0_block512(sx, W0n, b0n, h0, e0, mmax, b, t);
}

// ---- P5: final of flow 1 -> d_out
__global__ void __launch_bounds__(512)
k_fin1(const unsigned short* __restrict__ h1,
       const float* __restrict__ g1,
       const float* __restrict__ W2,   // flow 1
       const float* __restrict__ ld0,
       float* __restrict__ out_final,
       float* __restrict__ ld_final) {
    __shared__ float sh[NN];
    __shared__ float gf[DBLK];
    __shared__ float sx[DBLK];
    const int b = blockIdx.x;
    const int t = threadIdx.x;
    float ld = final_compute(h1, g1, W2, b, t, sh, gf, sx);
    if (t < DBLK) out_final[b * DBLK + t] = sx[t];
    if (t == 0) ld_final[b] = ld + ld0[b];
}

extern "C" void kernel_launch(void* const* d_in, const int* in_sizes, int n_in,
                              void* d_out, int out_size, void* d_ws, size_t ws_size,
                              hipStream_t stream) {
    const float* inp   = (const float*)d_in[0];
    const float* W0[2] = {(const float*)d_in[1], (const float*)d_in[6]};
    const float* W1[2] = {(const float*)d_in[2], (const float*)d_in[7]};
    const float* W2[2] = {(const float*)d_in[3], (const float*)d_in[8]};
    const float* b0[2] = {(const float*)d_in[4], (const float*)d_in[9]};
    const float* b1[2] = {(const float*)d_in[5], (const float*)d_in[10]};

    char* w = (char*)d_ws;
    size_t off = 0;
    unsigned short* W1bf = (unsigned short*)(w + off); off += (size_t)2 * NN * NN * 2; // 16 MB
    unsigned short* h0b  = (unsigned short*)(w + off); off += (size_t)BATCH * NN * 2;
    unsigned short* e0b  = (unsigned short*)(w + off); off += (size_t)BATCH * NN * 2;
    float* mmax = (float*)(w + off); off += (size_t)BATCH * DBLK * 4;
    unsigned short* h1 = (unsigned short*)(w + off); off += (size_t)BATCH * NN * 2;
    float* g1   = (float*)(w + off); off += (size_t)BATCH * NN * 4;
    float* ld0  = (float*)(w + off); off += (size_t)BATCH * 4;

    float* out_final = (float*)d_out;                 // (256,16)
    float* ld_final  = (float*)d_out + BATCH * DBLK;  // (256,)

    // P1: convert flow0 W1 (128 deep-pipelined blocks) + layer0 flow 0
    k_prep<<<dim3(384), dim3(512), 0, stream>>>(
        W1[0], W1bf, inp, W0[0], b0[0], h0b, e0b, mmax);

    // P2: layer1 flow 0 (2-bt tiles, dd descending) ∥ convert flow1 W1 (x<4)
    k_l1<true><<<dim3(20, 8, 4), dim3(512), 0, stream>>>(
        h0b, W1bf, b1[0], e0b, mmax, h1, g1,
        W1[1], W1bf + (size_t)NN * NN);

    // P3: final flow 0 + layer0 flow 1
    k_fin0<<<dim3(BATCH), dim3(512), 0, stream>>>(
        h1, g1, W2[0], W0[1], b0[1], h0b, e0b, mmax, ld0);

    // P4: layer1 flow 1 (2-bt tiles, dd descending)
    k_l1<false><<<dim3(16, 8, 4), dim3(512), 0, stream>>>(
        h0b, W1bf + (size_t)NN * NN, b1[1], e0b, mmax, h1, g1,
        nullptr, nullptr);

    // P5: final flow 1
    k_fin1<<<dim3(BATCH), dim3(512), 0, stream>>>(
        h1, g1, W2[1], ld0, out_final, ld_final);
}